// Round 21
// baseline (205.327 us; speedup 1.0000x reference)
//
#include <hip/hip_runtime.h>
#include <hip/hip_fp16.h>
#include <math.h>

#define TPB 256
#define TPBL 1024         // layer-kernel block size (16 waves/block; tests block-residency cap)
#define BIG 1024          // threads for hist/scatter kernels
#define G_CHUNKS 512      // edge chunks (one workgroup each in A and C)
#define NBCAP 1024        // max bins (128 nodes/bin => N <= 131072)
#define SCAP 7168         // max records staged per bin in D (56KB LDS, int2)
#define SCAP2 6272        // max records staged per chunk in C (50KB LDS, int2)
#define LAYER_BLOCKS 512  // persistent-style grid for layer kernels (2 blocks/CU)

// ===========================================================================
// Counting sort of edges by dst, bin = dst>>7 (128 nodes per bin).
// ONE 8B record per edge:
//   x = q0(14) | q1(14)<<14 | (q2&0xF)<<28        (u0,u1 @ q14; u2 @ q12)
//   y = src(17) | rel(7)<<17 | (q2>>4)<<24        (src < 2^17; N=100K ok)
// Bins 64B-aligned; pads live between bins, excluded via rowstart/rowend.
// scatterC: block-local LDS sort by bin + coalesced burst copy out.
// Layers: fp16 activations; R21: 1024-thread blocks (block-residency theory).
// ===========================================================================

// A: per-chunk LDS histogram -> hist[b*G + g]
__global__ void histA_kernel(const int* __restrict__ dst, int* __restrict__ hist,
                             int E, int CE, int NB) {
    __shared__ int lh[NBCAP];
    int g = blockIdx.x, t = threadIdx.x;
    for (int b = t; b < NBCAP; b += BIG) lh[b] = 0;
    __syncthreads();
    int e0 = g * CE, e1 = min(e0 + CE, E);
    for (int e = e0 + t; e < e1; e += BIG) atomicAdd(&lh[dst[e] >> 7], 1);
    __syncthreads();
    for (int b = t; b < NB; b += BIG) hist[b * G_CHUNKS + g] = lh[b];
}

// B1: block per bin: local exclusive scan of the chunk counts; per-bin total.
__global__ void base2_kernel(int* __restrict__ hist, int* __restrict__ bintotal) {
    __shared__ int buf[G_CHUNKS];
    int b = blockIdx.x, t = threadIdx.x;       // G_CHUNKS threads
    int v = hist[b * G_CHUNKS + t];
    buf[t] = v;
    __syncthreads();
    for (int off = 1; off < G_CHUNKS; off <<= 1) {
        int u = (t >= off) ? buf[t - off] : 0;
        __syncthreads();
        buf[t] += u;
        __syncthreads();
    }
    hist[b * G_CHUNKS + t] = buf[t] - v;       // local exclusive
    if (t == G_CHUNKS - 1) bintotal[b] = buf[t];
}

// B2: single-block scan over NB padded bin totals -> binstart[NB+1].
__global__ void scanB_kernel(const int* __restrict__ bintotal, int* __restrict__ binstart,
                             int NB) {
    __shared__ int buf[1024];
    int t = threadIdx.x;
    int v = (t < NB) ? ((bintotal[t] + 7) & ~7) : 0;   // pad each bin to 64B
    buf[t] = v;
    __syncthreads();
    for (int off = 1; off < 1024; off <<= 1) {
        int u = (t >= off) ? buf[t - off] : 0;
        __syncthreads();
        buf[t] += u;
        __syncthreads();
    }
    if (t < NB) binstart[t] = buf[t] - v;      // exclusive (aligned)
    if (t == 1023) binstart[NB] = buf[1023];
}

// C: block-local counting sort by bin in LDS, then coalesced burst copy out.
__global__ void scatterC_kernel(const int* __restrict__ src, const int* __restrict__ dst,
                                const float* __restrict__ ea, const int* __restrict__ hist,
                                const int* __restrict__ binstart,
                                int2* __restrict__ tmp, int E, int CE, int NB) {
    __shared__ int lbase[NBCAP];     // counts -> local exclusive bases
    __shared__ int laux[NBCAP];      // scan scratch -> cursors -> global slice bases
    __shared__ int2 stage[SCAP2];    // chunk records sorted by bin
    int g = blockIdx.x, t = threadIdx.x;
    int e0 = g * CE, e1 = min(e0 + CE, E);
    int total = e1 - e0;

    for (int b = t; b < NBCAP; b += BIG) lbase[b] = 0;
    __syncthreads();
    for (int e = e0 + t; e < e1; e += BIG) atomicAdd(&lbase[dst[e] >> 7], 1);
    __syncthreads();

    int c = lbase[t];
    laux[t] = c;
    __syncthreads();
    for (int off = 1; off < NBCAP; off <<= 1) {
        int u = (t >= off) ? laux[t - off] : 0;
        __syncthreads();
        laux[t] += u;
        __syncthreads();
    }
    int excl = laux[t] - c;
    __syncthreads();
    lbase[t] = excl;
    laux[t] = 0;                      // reset as cursors
    __syncthreads();

    for (int e = e0 + t; e < e1; e += BIG) {
        int d = dst[e];
        int b = d >> 7;
        int pos = lbase[b] + atomicAdd(&laux[b], 1);
        unsigned q0 = min((unsigned)(ea[(size_t)e * 3 + 0] * 16384.0f), 16383u);
        unsigned q1 = min((unsigned)(ea[(size_t)e * 3 + 1] * 16384.0f), 16383u);
        unsigned q2 = min((unsigned)(ea[(size_t)e * 3 + 2] * 4096.0f), 4095u);
        int2 rec;
        rec.x = (int)(q0 | (q1 << 14) | ((q2 & 0xFu) << 28));
        rec.y = (int)((unsigned)src[e] | ((unsigned)(d & 127) << 17) | ((q2 >> 4) << 24));
        stage[pos] = rec;
    }
    __syncthreads();

    for (int b = t; b < NB; b += BIG) laux[b] = binstart[b] + hist[b * G_CHUNKS + g];
    __syncthreads();
    for (int j = t; j < total; j += BIG) {
        int loB = 0, hiB = NB;        // largest b with lbase[b] <= j
        while (hiB - loB > 1) {
            int mid = (loB + hiB) >> 1;
            if (lbase[mid] <= j) loB = mid; else hiB = mid;
        }
        tmp[laux[loB] + (j - lbase[loB])] = stage[j];
    }
}

// C-fallback (direct random scatter) if a chunk exceeds SCAP2 (never for this input)
__global__ void scatterC_direct(const int* __restrict__ src, const int* __restrict__ dst,
                                const float* __restrict__ ea, const int* __restrict__ hist,
                                const int* __restrict__ binstart,
                                int2* __restrict__ tmp, int E, int CE, int NB) {
    __shared__ int lcur[NBCAP];
    int g = blockIdx.x, t = threadIdx.x;
    for (int b = t; b < NB; b += BIG) lcur[b] = binstart[b] + hist[b * G_CHUNKS + g];
    __syncthreads();
    int e0 = g * CE, e1 = min(e0 + CE, E);
    for (int e = e0 + t; e < e1; e += BIG) {
        int d = dst[e];
        int pos = atomicAdd(&lcur[d >> 7], 1);
        unsigned q0 = min((unsigned)(ea[(size_t)e * 3 + 0] * 16384.0f), 16383u);
        unsigned q1 = min((unsigned)(ea[(size_t)e * 3 + 1] * 16384.0f), 16383u);
        unsigned q2 = min((unsigned)(ea[(size_t)e * 3 + 2] * 4096.0f), 4095u);
        int2 rec;
        rec.x = (int)(q0 | (q1 << 14) | ((q2 & 0xFu) << 28));
        rec.y = (int)((unsigned)src[e] | ((unsigned)(d & 127) << 17) | ((q2 >> 4) << 24));
        tmp[pos] = rec;
    }
}

// D: per-bin sort by rel-node through LDS staging; aligned coalesced output;
//    emits per-node rowstart/rowend.
__global__ void binsortD_kernel(const int2* __restrict__ tmp,
                                const int* __restrict__ binstart,
                                const int* __restrict__ bintotal,
                                int2* __restrict__ perm,
                                int* __restrict__ rowstart, int* __restrict__ rowend,
                                int N, int NB) {
    __shared__ int2 stage[SCAP];
    __shared__ int h128[128], lcur[128];
    int b = blockIdx.x, t = threadIdx.x;      // TPB = 256
    int lo = binstart[b];
    int cnt = bintotal[b];
    int hi = lo + cnt;
    if (t < 128) h128[t] = 0;
    __syncthreads();
    for (int i = lo + t; i < hi; i += TPB) {
        unsigned y = (unsigned)tmp[i].y;
        atomicAdd(&h128[(y >> 17) & 127u], 1);
    }
    __syncthreads();
    if (t == 0) {
        int run = 0;
        for (int r = 0; r < 128; ++r) { int c = h128[r]; lcur[r] = run; run += c; }
    }
    __syncthreads();
    int n0 = b << 7;
    if (t < 128 && n0 + t < N) {
        rowstart[n0 + t] = lo + lcur[t];
        rowend[n0 + t]   = lo + lcur[t] + h128[t];
    }
    __syncthreads();                          // row writes before cursor mutation
    if (cnt <= SCAP) {
        for (int i = lo + t; i < hi; i += TPB) {
            int2 v = tmp[i];
            int pos = atomicAdd(&lcur[((unsigned)v.y >> 17) & 127u], 1);
            stage[pos] = v;
        }
        __syncthreads();
        for (int j = t; j < cnt; j += TPB) perm[lo + j] = stage[j];
    } else {
        for (int i = lo + t; i < hi; i += TPB) {
            int2 v = tmp[i];
            int pos = atomicAdd(&lcur[((unsigned)v.y >> 17) & 127u], 1);
            perm[lo + pos] = v;
        }
    }
}

// ---------------------------------------------------------------------------
// row-load helpers (fp32 or fp16 rows -> fp32 registers)
// ---------------------------------------------------------------------------
template<int CIN>
__device__ __forceinline__ void load_row(const float* p, float* hv) {
    if constexpr (CIN == 3) { hv[0] = p[0]; hv[1] = p[1]; hv[2] = p[2]; }
    else {
#pragma unroll
        for (int q = 0; q < CIN / 4; ++q) {
            float4 v = ((const float4*)p)[q];
            hv[4 * q + 0] = v.x; hv[4 * q + 1] = v.y;
            hv[4 * q + 2] = v.z; hv[4 * q + 3] = v.w;
        }
    }
}
template<int CIN>
__device__ __forceinline__ void load_row(const __half* p, float* hv) {
    if constexpr (CIN == 3) {
        hv[0] = __half2float(p[0]); hv[1] = __half2float(p[1]); hv[2] = __half2float(p[2]);
    } else {
#pragma unroll
        for (int q = 0; q < CIN / 8; ++q) {
            float4 v = ((const float4*)p)[q];               // 16B = 8 halves
            const __half2* hp = (const __half2*)&v;
#pragma unroll
            for (int j = 0; j < 4; ++j) {
                float2 f = __half22float2(hp[j]);
                hv[8 * q + 2 * j + 0] = f.x;
                hv[8 * q + 2 * j + 1] = f.y;
            }
        }
    }
}
__device__ __forceinline__ void store_out(float* p, float v)  { *p = v; }
__device__ __forceinline__ void store_out(__half* p, float v) { *p = __float2half(v); }

// ===========================================================================
// Fused layer: LPN=8 lanes per node.  T[i][k] = sum_e w_k(e) * h[src_e][i].
// R21: 1024-thread blocks + persistent grid (R17/R20 loop body unchanged).
// ===========================================================================
template<typename TIN, typename TOUT, int CIN, int COUT, bool ELU, int LPN>
__global__ __launch_bounds__(TPBL, 2)
void layer_kernel(const TIN* __restrict__ h,
                  const float* __restrict__ g,      // [CIN, 3*COUT]
                  const float* __restrict__ mu, const float* __restrict__ sigma,
                  const float* __restrict__ root,   // [CIN, COUT]
                  const float* __restrict__ bias,
                  const int* __restrict__ rowstart,
                  const int* __restrict__ rowend,
                  const int2* __restrict__ perm,
                  TOUT* __restrict__ out, int N, int nblk) {
    __shared__ float s_g[CIN * 3 * COUT];
    __shared__ float s_root[CIN * COUT];
    __shared__ float s_b[COUT];
    __shared__ float s_mu[9], s_gs[9];
    int t = threadIdx.x;
    for (int i = t; i < CIN * 3 * COUT; i += TPBL) s_g[i] = g[i];
    for (int i = t; i < CIN * COUT; i += TPBL) s_root[i] = root[i];
    if (t < COUT) s_b[t] = bias[t];
    if (t < 9) {
        s_mu[t] = mu[t];
        float sg = sigma[t];
        s_gs[t] = -0.5f / (1e-15f + sg * sg);
    }
    __syncthreads();

    for (int blk = blockIdx.x; blk < nblk; blk += gridDim.x) {
        int gid = blk * TPBL + t;
        int n = gid / LPN;
        int sub = gid & (LPN - 1);
        bool active = n < N;

        float T[CIN][3] = {};
        int e0 = 0, e1 = 0;
        if (active) { e0 = rowstart[n]; e1 = rowend[n]; }

        // 1-ahead perm prefetch (R17 body)
        int e = e0 + sub;
        int2 pnf;
        if (e < e1) pnf = perm[e];
        while (e < e1) {
            int2 p = pnf;
            int en = e + LPN;
            if (en < e1) pnf = perm[en];
            unsigned xw = (unsigned)p.x, yw = (unsigned)p.y;
            float u0 = ((float)(xw & 16383u) + 0.5f) * 6.103515625e-05f;      // /16384
            float u1 = ((float)((xw >> 14) & 16383u) + 0.5f) * 6.103515625e-05f;
            unsigned q2 = ((xw >> 28) & 0xFu) | (((yw >> 24) & 0xFFu) << 4);
            float u2 = ((float)q2 + 0.5f) * 2.44140625e-04f;                  // /4096
            unsigned s = yw & 0x1FFFFu;
            float w[3];
#pragma unroll
            for (int k = 0; k < 3; ++k) {
                float d0 = u0 - s_mu[3 * k + 0];
                float d1 = u1 - s_mu[3 * k + 1];
                float d2 = u2 - s_mu[3 * k + 2];
                w[k] = __expf(d0 * d0 * s_gs[3 * k + 0] +
                              d1 * d1 * s_gs[3 * k + 1] +
                              d2 * d2 * s_gs[3 * k + 2]);
            }
            float hv[CIN];
            load_row<CIN>(h + (size_t)s * CIN, hv);
#pragma unroll
            for (int i = 0; i < CIN; ++i) {
                T[i][0] = fmaf(hv[i], w[0], T[i][0]);
                T[i][1] = fmaf(hv[i], w[1], T[i][1]);
                T[i][2] = fmaf(hv[i], w[2], T[i][2]);
            }
            e = en;
        }

        // reduce T across the LPN lanes of this node (consecutive lanes)
#pragma unroll
        for (int i = 0; i < CIN; ++i)
#pragma unroll
            for (int k = 0; k < 3; ++k) {
                float v = T[i][k];
#pragma unroll
                for (int off = 1; off < LPN; off <<= 1)
                    v += __shfl_xor(v, off);
                T[i][k] = v;
            }

        if (active) {
            float invd = 1.0f / fmaxf((float)(e1 - e0), 1.0f);
            float hv2[CIN];
            load_row<CIN>(h + (size_t)n * CIN, hv2);
#pragma unroll
            for (int j = 0; j < (COUT + LPN - 1) / LPN; ++j) {
                int o = sub + LPN * j;
                if (o < COUT) {
                    float acc = 0.f;
#pragma unroll
                    for (int i = 0; i < CIN; ++i)
#pragma unroll
                        for (int k = 0; k < 3; ++k)
                            acc = fmaf(T[i][k], s_g[(i * 3 + k) * COUT + o], acc);
                    acc = acc * invd + s_b[o];
#pragma unroll
                    for (int i = 0; i < CIN; ++i)
                        acc = fmaf(hv2[i], s_root[i * COUT + o], acc);
                    if (ELU && acc < 0.f) acc = __expf(acc) - 1.0f;
                    store_out(out + (size_t)n * COUT + o, acc);
                }
            }
        }
    }
}

template<typename TIN, typename TOUT, int CIN, int COUT, bool ELU>
static void launch_layer(const TIN* hin, const float* g, const float* mu,
                         const float* sigma, const float* root, const float* b,
                         const int* rowstart, const int* rowend, const int2* perm,
                         TOUT* hout, int N, hipStream_t stream) {
    constexpr int LPN = 8;
    int nblk = (int)(((size_t)N * LPN + TPBL - 1) / TPBL);
    int grid = nblk < LAYER_BLOCKS ? nblk : LAYER_BLOCKS;
    layer_kernel<TIN, TOUT, CIN, COUT, ELU, LPN><<<grid, TPBL, 0, stream>>>(
        hin, g, mu, sigma, root, b, rowstart, rowend, perm, hout, N, nblk);
}

// ---------------------------------------------------------------------------
extern "C" void kernel_launch(void* const* d_in, const int* in_sizes, int n_in,
                              void* d_out, int out_size, void* d_ws, size_t ws_size,
                              hipStream_t stream) {
    const float* x  = (const float*)d_in[0];
    const int*   ei = (const int*)d_in[1];
    const float* ea = (const float*)d_in[2];

    const int N = in_sizes[0] / 3;
    const int E = in_sizes[2] / 3;
    const int* src = ei;
    const int* dst = ei + E;

    const float* g1 = (const float*)d_in[3];  const float* mu1 = (const float*)d_in[4];
    const float* s1 = (const float*)d_in[5];  const float* r1  = (const float*)d_in[6];
    const float* b1 = (const float*)d_in[7];
    const float* g2 = (const float*)d_in[8];  const float* mu2 = (const float*)d_in[9];
    const float* s2 = (const float*)d_in[10]; const float* r2  = (const float*)d_in[11];
    const float* b2 = (const float*)d_in[12];
    const float* g3 = (const float*)d_in[13]; const float* mu3 = (const float*)d_in[14];
    const float* s3 = (const float*)d_in[15]; const float* r3  = (const float*)d_in[16];
    const float* b3 = (const float*)d_in[17];
    const float* g4 = (const float*)d_in[18]; const float* mu4 = (const float*)d_in[19];
    const float* s4 = (const float*)d_in[20]; const float* r4  = (const float*)d_in[21];
    const float* b4 = (const float*)d_in[22];

    const int NB = (N + 127) >> 7;                   // 128-node bins (782 for N=100K)
    const int CE = (E + G_CHUNKS - 1) / G_CHUNKS;    // edges per chunk (6250)
    const int EPAD = E + 8 * NB;                     // record capacity incl. bin padding

    // workspace: rowstart | rowend | binstart | bintotal | tmp[EPAD] | perm[EPAD] | hA | hB | hist
    char* w = (char*)d_ws;
    int* rowstart = (int*)w;                          // N
    int* rowend   = rowstart + N;                     // N
    int* binstart = rowend + N;                       // NB+1
    int* bintotal = binstart + (NB + 1);              // NB
    size_t off = (((size_t)(2 * N + 2 * NB + 1)) * 4 + 63) & ~(size_t)63;
    int2* tmp  = (int2*)(w + off);                    // EPAD * 8B (64B-aligned)
    int2* perm = tmp + EPAD;                          // EPAD * 8B
    __half* hA = (__half*)(perm + EPAD);              // N*16 halves (fp16 activations)
    __half* hB = hA + (size_t)N * 16;                 // N*16 halves
    int* hist = (int*)(hB + (size_t)N * 16);          // NB*G ints (1.6MB)

    // counting sort by dst (no global atomics, coalesced scatter) + rowstart/rowend
    histA_kernel<<<G_CHUNKS, BIG, 0, stream>>>(dst, hist, E, CE, NB);
    base2_kernel<<<NB, G_CHUNKS, 0, stream>>>(hist, bintotal);
    scanB_kernel<<<1, 1024, 0, stream>>>(bintotal, binstart, NB);
    if (CE <= SCAP2) {
        scatterC_kernel<<<G_CHUNKS, BIG, 0, stream>>>(src, dst, ea, hist, binstart, tmp, E, CE, NB);
    } else {
        scatterC_direct<<<G_CHUNKS, BIG, 0, stream>>>(src, dst, ea, hist, binstart, tmp, E, CE, NB);
    }
    binsortD_kernel<<<NB, TPB, 0, stream>>>(tmp, binstart, bintotal, perm, rowstart, rowend, N, NB);

    float* out = (float*)d_out;

    launch_layer<float,  __half, 3,  8,  true >(x,  g1, mu1, s1, r1, b1, rowstart, rowend, perm, hA, N, stream);
    launch_layer<__half, __half, 8,  16, true >(hA, g2, mu2, s2, r2, b2, rowstart, rowend, perm, hB, N, stream);
    launch_layer<__half, __half, 16, 8,  true >(hB, g3, mu3, s3, r3, b3, rowstart, rowend, perm, hA, N, stream);
    launch_layer<__half, float,  8,  4,  false>(hA, g4, mu4, s4, r4, b4, rowstart, rowend, perm, out, N, stream);
}

// Round 22
// 179.975 us; speedup vs baseline: 1.1409x; 1.1409x over previous
//
#include <hip/hip_runtime.h>
#include <hip/hip_fp16.h>
#include <math.h>

#define TPB 256
#define BIG 1024          // threads for hist/scatter kernels
#define G_CHUNKS 512      // edge chunks (one workgroup each in A and C)
#define NBCAP 1024        // max bins (128 nodes/bin => N <= 131072)
#define SCAP 7168         // max records staged per bin in D (56KB LDS, int2)
#define SCAP2 6272        // max records staged per chunk in C (50KB LDS, int2)
#define LAYER_BLOCKS 2048 // persistent-style grid for layer kernels

// ===========================================================================
// Counting sort of edges by dst, bin = dst>>7 (128 nodes per bin).
// ONE 8B record per edge:
//   x = q0(14) | q1(14)<<14 | (q2&0xF)<<28        (u0,u1 @ q14; u2 @ q12)
//   y = src(17) | rel(7)<<17 | (q2>>4)<<24        (src < 2^17; N=100K ok)
// Bins 64B-aligned; pads live between bins, excluded via rowstart/rowend.
// scatterC: block-local LDS sort by bin + coalesced burst copy out.
// Layers: fp16 activations; grid-stride persistent blocks, R17 loop body.
// This is the R20 configuration — best measured (180.1us).
// ===========================================================================

// A: per-chunk LDS histogram -> hist[b*G + g]
__global__ void histA_kernel(const int* __restrict__ dst, int* __restrict__ hist,
                             int E, int CE, int NB) {
    __shared__ int lh[NBCAP];
    int g = blockIdx.x, t = threadIdx.x;
    for (int b = t; b < NBCAP; b += BIG) lh[b] = 0;
    __syncthreads();
    int e0 = g * CE, e1 = min(e0 + CE, E);
    for (int e = e0 + t; e < e1; e += BIG) atomicAdd(&lh[dst[e] >> 7], 1);
    __syncthreads();
    for (int b = t; b < NB; b += BIG) hist[b * G_CHUNKS + g] = lh[b];
}

// B1: block per bin: local exclusive scan of the chunk counts; per-bin total.
__global__ void base2_kernel(int* __restrict__ hist, int* __restrict__ bintotal) {
    __shared__ int buf[G_CHUNKS];
    int b = blockIdx.x, t = threadIdx.x;       // G_CHUNKS threads
    int v = hist[b * G_CHUNKS + t];
    buf[t] = v;
    __syncthreads();
    for (int off = 1; off < G_CHUNKS; off <<= 1) {
        int u = (t >= off) ? buf[t - off] : 0;
        __syncthreads();
        buf[t] += u;
        __syncthreads();
    }
    hist[b * G_CHUNKS + t] = buf[t] - v;       // local exclusive
    if (t == G_CHUNKS - 1) bintotal[b] = buf[t];
}

// B2: single-block scan over NB padded bin totals -> binstart[NB+1].
__global__ void scanB_kernel(const int* __restrict__ bintotal, int* __restrict__ binstart,
                             int NB) {
    __shared__ int buf[1024];
    int t = threadIdx.x;
    int v = (t < NB) ? ((bintotal[t] + 7) & ~7) : 0;   // pad each bin to 64B
    buf[t] = v;
    __syncthreads();
    for (int off = 1; off < 1024; off <<= 1) {
        int u = (t >= off) ? buf[t - off] : 0;
        __syncthreads();
        buf[t] += u;
        __syncthreads();
    }
    if (t < NB) binstart[t] = buf[t] - v;      // exclusive (aligned)
    if (t == 1023) binstart[NB] = buf[1023];
}

// C: block-local counting sort by bin in LDS, then coalesced burst copy out.
__global__ void scatterC_kernel(const int* __restrict__ src, const int* __restrict__ dst,
                                const float* __restrict__ ea, const int* __restrict__ hist,
                                const int* __restrict__ binstart,
                                int2* __restrict__ tmp, int E, int CE, int NB) {
    __shared__ int lbase[NBCAP];     // counts -> local exclusive bases
    __shared__ int laux[NBCAP];      // scan scratch -> cursors -> global slice bases
    __shared__ int2 stage[SCAP2];    // chunk records sorted by bin
    int g = blockIdx.x, t = threadIdx.x;
    int e0 = g * CE, e1 = min(e0 + CE, E);
    int total = e1 - e0;

    for (int b = t; b < NBCAP; b += BIG) lbase[b] = 0;
    __syncthreads();
    for (int e = e0 + t; e < e1; e += BIG) atomicAdd(&lbase[dst[e] >> 7], 1);
    __syncthreads();

    int c = lbase[t];
    laux[t] = c;
    __syncthreads();
    for (int off = 1; off < NBCAP; off <<= 1) {
        int u = (t >= off) ? laux[t - off] : 0;
        __syncthreads();
        laux[t] += u;
        __syncthreads();
    }
    int excl = laux[t] - c;
    __syncthreads();
    lbase[t] = excl;
    laux[t] = 0;                      // reset as cursors
    __syncthreads();

    for (int e = e0 + t; e < e1; e += BIG) {
        int d = dst[e];
        int b = d >> 7;
        int pos = lbase[b] + atomicAdd(&laux[b], 1);
        unsigned q0 = min((unsigned)(ea[(size_t)e * 3 + 0] * 16384.0f), 16383u);
        unsigned q1 = min((unsigned)(ea[(size_t)e * 3 + 1] * 16384.0f), 16383u);
        unsigned q2 = min((unsigned)(ea[(size_t)e * 3 + 2] * 4096.0f), 4095u);
        int2 rec;
        rec.x = (int)(q0 | (q1 << 14) | ((q2 & 0xFu) << 28));
        rec.y = (int)((unsigned)src[e] | ((unsigned)(d & 127) << 17) | ((q2 >> 4) << 24));
        stage[pos] = rec;
    }
    __syncthreads();

    for (int b = t; b < NB; b += BIG) laux[b] = binstart[b] + hist[b * G_CHUNKS + g];
    __syncthreads();
    for (int j = t; j < total; j += BIG) {
        int loB = 0, hiB = NB;        // largest b with lbase[b] <= j
        while (hiB - loB > 1) {
            int mid = (loB + hiB) >> 1;
            if (lbase[mid] <= j) loB = mid; else hiB = mid;
        }
        tmp[laux[loB] + (j - lbase[loB])] = stage[j];
    }
}

// C-fallback (direct random scatter) if a chunk exceeds SCAP2 (never for this input)
__global__ void scatterC_direct(const int* __restrict__ src, const int* __restrict__ dst,
                                const float* __restrict__ ea, const int* __restrict__ hist,
                                const int* __restrict__ binstart,
                                int2* __restrict__ tmp, int E, int CE, int NB) {
    __shared__ int lcur[NBCAP];
    int g = blockIdx.x, t = threadIdx.x;
    for (int b = t; b < NB; b += BIG) lcur[b] = binstart[b] + hist[b * G_CHUNKS + g];
    __syncthreads();
    int e0 = g * CE, e1 = min(e0 + CE, E);
    for (int e = e0 + t; e < e1; e += BIG) {
        int d = dst[e];
        int pos = atomicAdd(&lcur[d >> 7], 1);
        unsigned q0 = min((unsigned)(ea[(size_t)e * 3 + 0] * 16384.0f), 16383u);
        unsigned q1 = min((unsigned)(ea[(size_t)e * 3 + 1] * 16384.0f), 16383u);
        unsigned q2 = min((unsigned)(ea[(size_t)e * 3 + 2] * 4096.0f), 4095u);
        int2 rec;
        rec.x = (int)(q0 | (q1 << 14) | ((q2 & 0xFu) << 28));
        rec.y = (int)((unsigned)src[e] | ((unsigned)(d & 127) << 17) | ((q2 >> 4) << 24));
        tmp[pos] = rec;
    }
}

// D: per-bin sort by rel-node through LDS staging; aligned coalesced output;
//    emits per-node rowstart/rowend.
__global__ void binsortD_kernel(const int2* __restrict__ tmp,
                                const int* __restrict__ binstart,
                                const int* __restrict__ bintotal,
                                int2* __restrict__ perm,
                                int* __restrict__ rowstart, int* __restrict__ rowend,
                                int N, int NB) {
    __shared__ int2 stage[SCAP];
    __shared__ int h128[128], lcur[128];
    int b = blockIdx.x, t = threadIdx.x;      // TPB = 256
    int lo = binstart[b];
    int cnt = bintotal[b];
    int hi = lo + cnt;
    if (t < 128) h128[t] = 0;
    __syncthreads();
    for (int i = lo + t; i < hi; i += TPB) {
        unsigned y = (unsigned)tmp[i].y;
        atomicAdd(&h128[(y >> 17) & 127u], 1);
    }
    __syncthreads();
    if (t == 0) {
        int run = 0;
        for (int r = 0; r < 128; ++r) { int c = h128[r]; lcur[r] = run; run += c; }
    }
    __syncthreads();
    int n0 = b << 7;
    if (t < 128 && n0 + t < N) {
        rowstart[n0 + t] = lo + lcur[t];
        rowend[n0 + t]   = lo + lcur[t] + h128[t];
    }
    __syncthreads();                          // row writes before cursor mutation
    if (cnt <= SCAP) {
        for (int i = lo + t; i < hi; i += TPB) {
            int2 v = tmp[i];
            int pos = atomicAdd(&lcur[((unsigned)v.y >> 17) & 127u], 1);
            stage[pos] = v;
        }
        __syncthreads();
        for (int j = t; j < cnt; j += TPB) perm[lo + j] = stage[j];
    } else {
        for (int i = lo + t; i < hi; i += TPB) {
            int2 v = tmp[i];
            int pos = atomicAdd(&lcur[((unsigned)v.y >> 17) & 127u], 1);
            perm[lo + pos] = v;
        }
    }
}

// ---------------------------------------------------------------------------
// row-load helpers (fp32 or fp16 rows -> fp32 registers)
// ---------------------------------------------------------------------------
template<int CIN>
__device__ __forceinline__ void load_row(const float* p, float* hv) {
    if constexpr (CIN == 3) { hv[0] = p[0]; hv[1] = p[1]; hv[2] = p[2]; }
    else {
#pragma unroll
        for (int q = 0; q < CIN / 4; ++q) {
            float4 v = ((const float4*)p)[q];
            hv[4 * q + 0] = v.x; hv[4 * q + 1] = v.y;
            hv[4 * q + 2] = v.z; hv[4 * q + 3] = v.w;
        }
    }
}
template<int CIN>
__device__ __forceinline__ void load_row(const __half* p, float* hv) {
    if constexpr (CIN == 3) {
        hv[0] = __half2float(p[0]); hv[1] = __half2float(p[1]); hv[2] = __half2float(p[2]);
    } else {
#pragma unroll
        for (int q = 0; q < CIN / 8; ++q) {
            float4 v = ((const float4*)p)[q];               // 16B = 8 halves
            const __half2* hp = (const __half2*)&v;
#pragma unroll
            for (int j = 0; j < 4; ++j) {
                float2 f = __half22float2(hp[j]);
                hv[8 * q + 2 * j + 0] = f.x;
                hv[8 * q + 2 * j + 1] = f.y;
            }
        }
    }
}
__device__ __forceinline__ void store_out(float* p, float v)  { *p = v; }
__device__ __forceinline__ void store_out(__half* p, float v) { *p = __float2half(v); }

// ===========================================================================
// Fused layer: LPN=8 lanes per node.  T[i][k] = sum_e w_k(e) * h[src_e][i].
// Grid-stride persistent blocks (LAYER_BLOCKS fixed grid) + R17 loop body
// (1-ahead perm prefetch) — best measured variant (R20).
// ===========================================================================
template<typename TIN, typename TOUT, int CIN, int COUT, bool ELU, int LPN>
__global__ void layer_kernel(const TIN* __restrict__ h,
                             const float* __restrict__ g,      // [CIN, 3*COUT]
                             const float* __restrict__ mu, const float* __restrict__ sigma,
                             const float* __restrict__ root,   // [CIN, COUT]
                             const float* __restrict__ bias,
                             const int* __restrict__ rowstart,
                             const int* __restrict__ rowend,
                             const int2* __restrict__ perm,
                             TOUT* __restrict__ out, int N, int nblk) {
    __shared__ float s_g[CIN * 3 * COUT];
    __shared__ float s_root[CIN * COUT];
    __shared__ float s_b[COUT];
    __shared__ float s_mu[9], s_gs[9];
    int t = threadIdx.x;
    for (int i = t; i < CIN * 3 * COUT; i += TPB) s_g[i] = g[i];
    for (int i = t; i < CIN * COUT; i += TPB) s_root[i] = root[i];
    if (t < COUT) s_b[t] = bias[t];
    if (t < 9) {
        s_mu[t] = mu[t];
        float sg = sigma[t];
        s_gs[t] = -0.5f / (1e-15f + sg * sg);
    }
    __syncthreads();

    for (int blk = blockIdx.x; blk < nblk; blk += gridDim.x) {
        int gid = blk * TPB + t;
        int n = gid / LPN;
        int sub = gid & (LPN - 1);
        bool active = n < N;

        float T[CIN][3] = {};
        int e0 = 0, e1 = 0;
        if (active) { e0 = rowstart[n]; e1 = rowend[n]; }

        // 1-ahead perm prefetch (R17 body)
        int e = e0 + sub;
        int2 pnf;
        if (e < e1) pnf = perm[e];
        while (e < e1) {
            int2 p = pnf;
            int en = e + LPN;
            if (en < e1) pnf = perm[en];
            unsigned xw = (unsigned)p.x, yw = (unsigned)p.y;
            float u0 = ((float)(xw & 16383u) + 0.5f) * 6.103515625e-05f;      // /16384
            float u1 = ((float)((xw >> 14) & 16383u) + 0.5f) * 6.103515625e-05f;
            unsigned q2 = ((xw >> 28) & 0xFu) | (((yw >> 24) & 0xFFu) << 4);
            float u2 = ((float)q2 + 0.5f) * 2.44140625e-04f;                  // /4096
            unsigned s = yw & 0x1FFFFu;
            float w[3];
#pragma unroll
            for (int k = 0; k < 3; ++k) {
                float d0 = u0 - s_mu[3 * k + 0];
                float d1 = u1 - s_mu[3 * k + 1];
                float d2 = u2 - s_mu[3 * k + 2];
                w[k] = __expf(d0 * d0 * s_gs[3 * k + 0] +
                              d1 * d1 * s_gs[3 * k + 1] +
                              d2 * d2 * s_gs[3 * k + 2]);
            }
            float hv[CIN];
            load_row<CIN>(h + (size_t)s * CIN, hv);
#pragma unroll
            for (int i = 0; i < CIN; ++i) {
                T[i][0] = fmaf(hv[i], w[0], T[i][0]);
                T[i][1] = fmaf(hv[i], w[1], T[i][1]);
                T[i][2] = fmaf(hv[i], w[2], T[i][2]);
            }
            e = en;
        }

        // reduce T across the LPN lanes of this node (consecutive lanes)
#pragma unroll
        for (int i = 0; i < CIN; ++i)
#pragma unroll
            for (int k = 0; k < 3; ++k) {
                float v = T[i][k];
#pragma unroll
                for (int off = 1; off < LPN; off <<= 1)
                    v += __shfl_xor(v, off);
                T[i][k] = v;
            }

        if (active) {
            float invd = 1.0f / fmaxf((float)(e1 - e0), 1.0f);
            float hv2[CIN];
            load_row<CIN>(h + (size_t)n * CIN, hv2);
#pragma unroll
            for (int j = 0; j < (COUT + LPN - 1) / LPN; ++j) {
                int o = sub + LPN * j;
                if (o < COUT) {
                    float acc = 0.f;
#pragma unroll
                    for (int i = 0; i < CIN; ++i)
#pragma unroll
                        for (int k = 0; k < 3; ++k)
                            acc = fmaf(T[i][k], s_g[(i * 3 + k) * COUT + o], acc);
                    acc = acc * invd + s_b[o];
#pragma unroll
                    for (int i = 0; i < CIN; ++i)
                        acc = fmaf(hv2[i], s_root[i * COUT + o], acc);
                    if (ELU && acc < 0.f) acc = __expf(acc) - 1.0f;
                    store_out(out + (size_t)n * COUT + o, acc);
                }
            }
        }
    }
}

template<typename TIN, typename TOUT, int CIN, int COUT, bool ELU>
static void launch_layer(const TIN* hin, const float* g, const float* mu,
                         const float* sigma, const float* root, const float* b,
                         const int* rowstart, const int* rowend, const int2* perm,
                         TOUT* hout, int N, hipStream_t stream) {
    constexpr int LPN = 8;
    int nblk = (int)(((size_t)N * LPN + TPB - 1) / TPB);
    int grid = nblk < LAYER_BLOCKS ? nblk : LAYER_BLOCKS;
    layer_kernel<TIN, TOUT, CIN, COUT, ELU, LPN><<<grid, TPB, 0, stream>>>(
        hin, g, mu, sigma, root, b, rowstart, rowend, perm, hout, N, nblk);
}

// ---------------------------------------------------------------------------
extern "C" void kernel_launch(void* const* d_in, const int* in_sizes, int n_in,
                              void* d_out, int out_size, void* d_ws, size_t ws_size,
                              hipStream_t stream) {
    const float* x  = (const float*)d_in[0];
    const int*   ei = (const int*)d_in[1];
    const float* ea = (const float*)d_in[2];

    const int N = in_sizes[0] / 3;
    const int E = in_sizes[2] / 3;
    const int* src = ei;
    const int* dst = ei + E;

    const float* g1 = (const float*)d_in[3];  const float* mu1 = (const float*)d_in[4];
    const float* s1 = (const float*)d_in[5];  const float* r1  = (const float*)d_in[6];
    const float* b1 = (const float*)d_in[7];
    const float* g2 = (const float*)d_in[8];  const float* mu2 = (const float*)d_in[9];
    const float* s2 = (const float*)d_in[10]; const float* r2  = (const float*)d_in[11];
    const float* b2 = (const float*)d_in[12];
    const float* g3 = (const float*)d_in[13]; const float* mu3 = (const float*)d_in[14];
    const float* s3 = (const float*)d_in[15]; const float* r3  = (const float*)d_in[16];
    const float* b3 = (const float*)d_in[17];
    const float* g4 = (const float*)d_in[18]; const float* mu4 = (const float*)d_in[19];
    const float* s4 = (const float*)d_in[20]; const float* r4  = (const float*)d_in[21];
    const float* b4 = (const float*)d_in[22];

    const int NB = (N + 127) >> 7;                   // 128-node bins (782 for N=100K)
    const int CE = (E + G_CHUNKS - 1) / G_CHUNKS;    // edges per chunk (6250)
    const int EPAD = E + 8 * NB;                     // record capacity incl. bin padding

    // workspace: rowstart | rowend | binstart | bintotal | tmp[EPAD] | perm[EPAD] | hA | hB | hist
    char* w = (char*)d_ws;
    int* rowstart = (int*)w;                          // N
    int* rowend   = rowstart + N;                     // N
    int* binstart = rowend + N;                       // NB+1
    int* bintotal = binstart + (NB + 1);              // NB
    size_t off = (((size_t)(2 * N + 2 * NB + 1)) * 4 + 63) & ~(size_t)63;
    int2* tmp  = (int2*)(w + off);                    // EPAD * 8B (64B-aligned)
    int2* perm = tmp + EPAD;                          // EPAD * 8B
    __half* hA = (__half*)(perm + EPAD);              // N*16 halves (fp16 activations)
    __half* hB = hA + (size_t)N * 16;                 // N*16 halves
    int* hist = (int*)(hB + (size_t)N * 16);          // NB*G ints (1.6MB)

    // counting sort by dst (no global atomics, coalesced scatter) + rowstart/rowend
    histA_kernel<<<G_CHUNKS, BIG, 0, stream>>>(dst, hist, E, CE, NB);
    base2_kernel<<<NB, G_CHUNKS, 0, stream>>>(hist, bintotal);
    scanB_kernel<<<1, 1024, 0, stream>>>(bintotal, binstart, NB);
    if (CE <= SCAP2) {
        scatterC_kernel<<<G_CHUNKS, BIG, 0, stream>>>(src, dst, ea, hist, binstart, tmp, E, CE, NB);
    } else {
        scatterC_direct<<<G_CHUNKS, BIG, 0, stream>>>(src, dst, ea, hist, binstart, tmp, E, CE, NB);
    }
    binsortD_kernel<<<NB, TPB, 0, stream>>>(tmp, binstart, bintotal, perm, rowstart, rowend, N, NB);

    float* out = (float*)d_out;

    launch_layer<float,  __half, 3,  8,  true >(x,  g1, mu1, s1, r1, b1, rowstart, rowend, perm, hA, N, stream);
    launch_layer<__half, __half, 8,  16, true >(hA, g2, mu2, s2, r2, b2, rowstart, rowend, perm, hB, N, stream);
    launch_layer<__half, __half, 16, 8,  true >(hB, g3, mu3, s3, r3, b3, rowstart, rowend, perm, hA, N, stream);
    launch_layer<__half, float,  8,  4,  false>(hA, g4, mu4, s4, r4, b4, rowstart, rowend, perm, out, N, stream);
}